// Round 10
// baseline (798.194 us; speedup 1.0000x reference)
//
#include <hip/hip_runtime.h>
#include <hip/hip_bf16.h>
#include <math.h>

#define D_MODEL   1024
#define D_INNER   2048
#define D_STATE   128
#define NHEADS    32
#define HEADDIM   64
#define DCONV     4
#define CONV_DIM  (D_INNER + 2 * D_STATE)              // 2304
#define D_IN_PROJ (2 * D_INNER + 2 * D_STATE + NHEADS) // 4384
#define NBLOCKS   4
#define BATCH     4
#define SEQ       512
#define NTOK      (BATCH * SEQ)                        // 2048
#define STATE_IN  510
#define NPAD_IN   4480
#define NSEG      8
#define SEGLEN    64
#define NBH       (BATCH * NHEADS)                     // 128
#define OFF_B     D_INNER                              // 2048
#define OFF_C     (D_INNER + D_STATE)                  // 2176
#define OFF_DT    (D_IN_PROJ - NHEADS)

typedef _Float16 half8_t __attribute__((ext_vector_type(8)));
typedef float f32x4_t  __attribute__((ext_vector_type(4)));
typedef unsigned short us;
typedef unsigned short us8 __attribute__((ext_vector_type(8)));

__device__ __forceinline__ us f2h(float f) {
    _Float16 h = (_Float16)f;
    return __builtin_bit_cast(us, h);
}
__device__ __forceinline__ float h2f(us u) {
    return (float)__builtin_bit_cast(_Float16, u);
}
__device__ __forceinline__ void gl2lds16(const us* gp, us* lp) {
    __builtin_amdgcn_global_load_lds(
        (const __attribute__((address_space(1))) unsigned int*)(gp),
        (__attribute__((address_space(3))) unsigned int*)(lp), 16, 0, 0);
}

// ---------------------------------------------------------------------------
// concat -> hcat [NTOK, 512] fp16
// ---------------------------------------------------------------------------
__global__ void concat_kernel(const float* __restrict__ x,
                              const float* __restrict__ steps,
                              const float* __restrict__ curr,
                              us* __restrict__ hcat)
{
    int idx = blockIdx.x * 256 + threadIdx.x;
    if (idx >= NTOK * 512) return;
    int bl = idx >> 9;
    int c  = idx & 511;
    float v;
    if (c < STATE_IN)       v = x[(size_t)bl * STATE_IN + c];
    else if (c == STATE_IN) v = steps[bl];
    else                    v = curr[bl];
    hcat[idx] = f2h(v);
}

// ---------------------------------------------------------------------------
// ALL weight transposes, ONE dispatch, REGISTERS ONLY (no LDS, no barrier).
// Each thread transposes an 8k x 4n micro-tile: 8 independent float4 loads,
// 4 x 16B us8 stores where 8 consecutive lanes form a 128 B contiguous chunk.
// Block tile: 64k x 128n.  W[K,N] fp32 -> WT[Npad,K] fp16.  Tile ranges:
//   [0,32)       mi_w1   K=512  N=512   ntx=4
//   [32,96)      mi_w2   K=512  N=1024  ntx=8
//   [96,2336)    W_in i  K=1024 N=4384  ntx=35 (pad to 4480: zero-fill)
//   [2336,3360)  W_out i K=2048 N=1024  ntx=8
//   [3360,3488)  mo_w1   K=1024 N=1024  ntx=8
// ---------------------------------------------------------------------------
#define NT_TRANS 3488
__global__ __launch_bounds__(256)
void transpose_all_kernel(const float* __restrict__ mi_w1, const float* __restrict__ mi_w2,
                          const float* __restrict__ W_in, const float* __restrict__ W_out,
                          const float* __restrict__ mo_w1,
                          us* __restrict__ wt_mi1, us* __restrict__ wt_mi2,
                          us* __restrict__ wt_in, us* __restrict__ wt_out,
                          us* __restrict__ wt_mo1)
{
    int bid = blockIdx.x;
    const float* W; us* WT; int K, N, ntx, r;
    if (bid < 32)        { W = mi_w1; WT = wt_mi1; K = 512;  N = 512;  ntx = 4; r = bid; }
    else if (bid < 96)   { W = mi_w2; WT = wt_mi2; K = 512;  N = 1024; ntx = 8; r = bid - 32; }
    else if (bid < 2336) {
        int rel = bid - 96, i = rel / 560;
        r = rel - i * 560;
        W  = W_in  + (size_t)i * D_MODEL * D_IN_PROJ;
        WT = wt_in + (size_t)i * NPAD_IN * 1024;
        K = 1024; N = D_IN_PROJ; ntx = 35;
    }
    else if (bid < 3360) {
        int rel = bid - 2336, i = rel / 256;
        r = rel - i * 256;
        W  = W_out  + (size_t)i * D_INNER * D_MODEL;
        WT = wt_out + (size_t)i * 1024 * 2048;
        K = 2048; N = 1024; ntx = 8;
    }
    else { W = mo_w1; WT = wt_mo1; K = 1024; N = 1024; ntx = 8; r = bid - 3360; }
    int n0 = (r % ntx) * 128, k0 = (r / ntx) * 64;

    int t = threadIdx.x;
    int ko = t & 7;            // k-octet within 64-row tile
    int nq = t >> 3;           // n-quad within 128-col tile (0..31)
    int n  = n0 + nq * 4;
    int k  = k0 + ko * 8;

    float4 v[8];
    if (n < N) {
        const float* src = W + (size_t)k * N + n;
#pragma unroll
        for (int j = 0; j < 8; ++j)
            v[j] = *(const float4*)(src + (size_t)j * N);
    } else {
#pragma unroll
        for (int j = 0; j < 8; ++j) v[j] = make_float4(0.f, 0.f, 0.f, 0.f);
    }
#pragma unroll
    for (int q = 0; q < 4; ++q) {
        us8 o;
#pragma unroll
        for (int j = 0; j < 8; ++j) o[j] = f2h(((const float*)&v[j])[q]);
        *(us8*)(WT + (size_t)(n + q) * K + k) = o;
    }
}

// ---------------------------------------------------------------------------
// fp16 MFMA GEMM, triple-buffered K-pipeline, UNROLLED x3 (static LDS bases).
// body(t): wait vmcnt(L) -> s_barrier -> stage(t+2) -> compute(t)
// L = loads/tile/wave = BM/64 + BN/64; steady-state wait = vmcnt(L).
// XCD-aware block swizzle (T1).
// ---------------------------------------------------------------------------
#define PHASE(TT, CUR, STG)                                                     \
    {                                                                           \
        if ((TT) == NT - 1)                                                     \
            asm volatile("s_waitcnt vmcnt(0)" ::: "memory");                    \
        else if constexpr (BM / 64 + BN / 64 == 4)                              \
            asm volatile("s_waitcnt vmcnt(4)" ::: "memory");                    \
        else if constexpr (BM / 64 + BN / 64 == 3)                              \
            asm volatile("s_waitcnt vmcnt(3)" ::: "memory");                    \
        else                                                                    \
            asm volatile("s_waitcnt vmcnt(2)" ::: "memory");                    \
        __builtin_amdgcn_s_barrier();                                           \
        if ((TT) + 2 < NT) stage(STG, ((TT) + 2) << 5);                         \
        half8_t af[TI], bfr[4];                                                 \
        _Pragma("unroll")                                                       \
        for (int ti = 0; ti < TI; ++ti) {                                       \
            int rr = wr + ti * 16 + l16;                                        \
            af[ti] = *(const half8_t*)&Al[CUR][rr * 32 + ((g ^ ((rr >> 2) & 3)) * 8)]; \
        }                                                                       \
        _Pragma("unroll")                                                       \
        for (int tj = 0; tj < 4; ++tj) {                                        \
            int rr = wc + tj * 16 + l16;                                        \
            bfr[tj] = *(const half8_t*)&Bl[CUR][rr * 32 + ((g ^ ((rr >> 2) & 3)) * 8)]; \
        }                                                                       \
        _Pragma("unroll")                                                       \
        for (int ti = 0; ti < TI; ++ti)                                         \
            _Pragma("unroll")                                                   \
            for (int tj = 0; tj < 4; ++tj)                                      \
                acc[ti][tj] = __builtin_amdgcn_mfma_f32_16x16x32_f16(           \
                    af[ti], bfr[tj], acc[ti][tj], 0, 0, 0);                     \
    }

template<int BM, int BN, int TI>
__global__ __launch_bounds__(256)
void mfma_gemm_f16(const us* __restrict__ A, const us* __restrict__ BT,
                   const float* __restrict__ bias, us* __restrict__ C,
                   int N, int K, int relu)
{
    __shared__ __attribute__((aligned(16))) us Al[3][BM * 32];
    __shared__ __attribute__((aligned(16))) us Bl[3][BN * 32];
    const int tid = threadIdx.x, lane = tid & 63, wave = tid >> 6;
    const int g = lane >> 4, l16 = lane & 15;
    const int wr = (BN == 128) ? (wave >> 1) * 64 : wave * (BM / 4);
    const int wc = (BN == 128) ? (wave & 1) * 64 : 0;

    // XCD-aware swizzle (bijective when nwg % 8 == 0; identity otherwise)
    int bx = blockIdx.x, by = blockIdx.y;
    {
        int nbx = gridDim.x;
        int nwg = nbx * gridDim.y;
        if (!(nwg & 7)) {
            int id  = by * nbx + bx;
            int swz = (id & 7) * (nwg >> 3) + (id >> 3);
            bx = swz % nbx;
            by = swz / nbx;
        }
    }
    const int m0 = by * BM, n0 = bx * BN;
    const int lrow = lane >> 2;
    const int lcol = ((lane & 3) ^ ((lrow >> 2) & 3)) * 8;

    f32x4_t acc[TI][4];
    const f32x4_t zero = {0.f, 0.f, 0.f, 0.f};
#pragma unroll
    for (int i = 0; i < TI; ++i)
#pragma unroll
        for (int j = 0; j < 4; ++j) acc[i][j] = zero;

    const us* abase = A  + (size_t)m0 * K;
    const us* bbase = BT + (size_t)n0 * K;

    auto stage = [&](int buf, int k0) {
#pragma unroll
        for (int s = 0; s < BM / 64; ++s) {
            int rb = wave * (BM / 4) + s * 16;
            gl2lds16(abase + (size_t)(rb + lrow) * K + k0 + lcol, &Al[buf][rb * 32]);
        }
#pragma unroll
        for (int s = 0; s < BN / 64; ++s) {
            int rb = wave * (BN / 4) + s * 16;
            gl2lds16(bbase + (size_t)(rb + lrow) * K + k0 + lcol, &Bl[buf][rb * 32]);
        }
    };

    const int NT = K >> 5;
    stage(0, 0);
    stage(1, 32);

    for (int t = 0; t < NT; t += 3) {
        PHASE(t, 0, 2)
        if (t + 1 < NT) PHASE(t + 1, 1, 0)
        if (t + 2 < NT) PHASE(t + 2, 2, 1)
    }

#pragma unroll
    for (int tj = 0; tj < 4; ++tj) {
        int col = n0 + wc + tj * 16 + l16;
        if (col >= N) continue;
        float bv = bias ? bias[col] : 0.f;
#pragma unroll
        for (int ti = 0; ti < TI; ++ti) {
            int rbase = m0 + wr + ti * 16 + g * 4;
#pragma unroll
            for (int r = 0; r < 4; ++r) {
                float v = acc[ti][tj][r] + bv;
                if (relu) v = fmaxf(v, 0.f);
                C[(size_t)(rbase + r) * N + col] = f2h(v);
            }
        }
    }
}

// ---------------------------------------------------------------------------
// causal depthwise conv1d (k=4) + SiLU; vectorized 8 channels/thread
// (16 B/lane loads, G13 coalescing sweet spot)
// ---------------------------------------------------------------------------
__global__ __launch_bounds__(256)
void conv_silu_kernel(const us* __restrict__ zxbcdt,
                      const float* __restrict__ cw,
                      const float* __restrict__ cb,
                      us* __restrict__ xBCc)
{
    int idx = blockIdx.x * 256 + threadIdx.x;          // octet index
    if (idx >= NTOK * (CONV_DIM / 8)) return;
    int cq = idx % (CONV_DIM / 8);
    int bl = idx / (CONV_DIM / 8);
    int b  = bl >> 9;
    int l  = bl & 511;
    int c  = cq * 8;
    float acc[8];
#pragma unroll
    for (int e = 0; e < 8; ++e) acc[e] = cb[c + e];
    const us* base = zxbcdt + (size_t)(b * SEQ) * D_IN_PROJ + D_INNER + c;
#pragma unroll
    for (int k = 0; k < DCONV; ++k) {
        int ll = l + k - (DCONV - 1);
        if (ll >= 0) {
            us8 u = *(const us8*)(base + (size_t)ll * D_IN_PROJ);
#pragma unroll
            for (int e = 0; e < 8; ++e)
                acc[e] = fmaf(h2f(u[e]), cw[(c + e) * DCONV + k], acc[e]);
        }
    }
    us8 o;
#pragma unroll
    for (int e = 0; e < 8; ++e)
        o[e] = f2h(acc[e] / (1.f + __expf(-acc[e])));
    *(us8*)(xBCc + (size_t)bl * CONV_DIM + c) = o;
}

// ---------------------------------------------------------------------------
// PASS 1 (MFMA chunked SSD): one block per (b,h,seg); 256 threads = 4 waves.
// ---------------------------------------------------------------------------
__global__ __launch_bounds__(256)
void scan_seg_mfma_kernel(const us* __restrict__ zx, const us* __restrict__ xc,
                          const float* __restrict__ dt_bias,
                          const float* __restrict__ A_log,
                          const float* __restrict__ D_skip,
                          float* __restrict__ y, float* __restrict__ alpha,
                          us* __restrict__ Hseg)
{
    __shared__ __attribute__((aligned(16))) us Csh[64 * 128];  // P1 A; aliased by Ssh
    __shared__ __attribute__((aligned(16))) us Bsh[64 * 128];  // P1 B
    __shared__ __attribute__((aligned(16))) us Bt[128 * 64];   // B^T [n][j], P3
    __shared__ __attribute__((aligned(16))) us Xt[64 * 64];    // X^T [p][j], P2/P3
    __shared__ float dt_s[64], ls[64], csc[64];
    us* Ssh = Csh;                                             // S' [i][j] (8 KB of 16)
    const int bi = blockIdx.x, bh = bi >> 3, seg = bi & 7;
    const int b = bh >> 5, h = bh & 31;
    const int tid = threadIdx.x, lane = tid & 63, w = tid >> 6;
    const int g = lane >> 4, l16 = lane & 15;
    const int t0g = seg * SEGLEN;
    const size_t rowbase = (size_t)(b * SEQ + t0g);

    // --- async DMA staging of C and B tiles (row-major, swizzled) ---
    {
        int rr = lane >> 4, s = lane & 15;
#pragma unroll
        for (int it = 0; it < 4; ++it) {
            int rb = w * 16 + it * 4;
            int row = rb + rr;
            const us* src = xc + (rowbase + row) * CONV_DIM;
            int sw = (s ^ (row & 7)) * 8;
            gl2lds16(src + OFF_C + sw, &Csh[rb * 128]);
            gl2lds16(src + OFF_B + sw, &Bsh[rb * 128]);
        }
    }
    // --- VGPR transpose staging: Xt[p][j] ---
#pragma unroll
    for (int qi = 0; qi < 4; ++qi) {
        int idx = tid + qi * 256;          // 1024 quads
        int pq = idx & 15, j = idx >> 4;
        ushort4 v = *(const ushort4*)(xc + (rowbase + j) * CONV_DIM + h * 64 + pq * 4);
#pragma unroll
        for (int e = 0; e < 4; ++e) {
            int p = pq * 4 + e;
            int pc = ((((j >> 3) ^ (p & 7)) << 3) | (j & 7));
            Xt[p * 64 + pc] = ((const us*)&v)[e];
        }
    }
    // --- VGPR transpose staging: Bt[n][j] ---
#pragma unroll
    for (int qi = 0; qi < 8; ++qi) {
        int idx = tid + qi * 256;          // 2048 quads
        int nq = idx & 31, j = idx >> 5;
        ushort4 v = *(const ushort4*)(xc + (rowbase + j) * CONV_DIM + OFF_B + nq * 4);
#pragma unroll
        for (int e = 0; e < 4; ++e) {
            int n = nq * 4 + e;
            int pc = ((((j >> 3) ^ (n & 7)) << 3) | (j & 7));
            Bt[n * 64 + pc] = ((const us*)&v)[e];
        }
    }
    // --- dt / cumulative decay (wave 0) ---
    if (tid < 64) {
        int j = tid;
        float dtraw = h2f(zx[(rowbase + j) * D_IN_PROJ + OFF_DT + h]) + dt_bias[h];
        float dtv = (dtraw > 20.f) ? dtraw : log1pf(expf(dtraw));
        float ld = dtv * (-expf(A_log[h]));
#pragma unroll
        for (int o = 1; o < 64; o <<= 1) {
            float v = __shfl_up(ld, o);
            if (j >= o) ld += v;
        }
        float al = expf(ld);
        dt_s[j] = dtv;
        ls[j] = ld;
        alpha[(size_t)bh * SEQ + t0g + j] = al;
        float cend = __shfl(ld, 63);
        csc[j] = dtv * expf(cend - ld);
    }
    __syncthreads();   // DMA drained (vmcnt0 before barrier) + stagings visible

    const float Dsk = D_skip[h];
    const f32x4_t vzero = {0.f, 0.f, 0.f, 0.f};

    // --- P1: G = C.B^T ---
    f32x4_t acc1[4];
#pragma unroll
    for (int jt = 0; jt < 4; ++jt) acc1[jt] = vzero;
    {
        int ia = w * 16 + l16;
#pragma unroll
        for (int ks = 0; ks < 4; ++ks) {
            half8_t a = *(const half8_t*)&Csh[ia * 128 + (((ks * 4 + g) ^ (ia & 7)) << 3)];
#pragma unroll
            for (int jt = 0; jt < 4; ++jt) {
                int jr = jt * 16 + l16;
                half8_t bfr = *(const half8_t*)&Bsh[jr * 128 + (((ks * 4 + g) ^ (jr & 7)) << 3)];
                acc1[jt] = __builtin_amdgcn_mfma_f32_16x16x32_f16(a, bfr, acc1[jt], 0, 0, 0);
            }
        }
    }
    __syncthreads();   // all waves done reading Csh before Ssh overwrites it

    // --- S' mask/scale -> Ssh (aliases Csh) ---
    {
        int i0 = w * 16 + g * 4;
        float lsi[4];
#pragma unroll
        for (int r = 0; r < 4; ++r) lsi[r] = ls[i0 + r];
#pragma unroll
        for (int jt = 0; jt < 4; ++jt) {
            int j = jt * 16 + l16;
            float lj = ls[j], dj = dt_s[j];
#pragma unroll
            for (int r = 0; r < 4; ++r) {
                int i = i0 + r;
                float v = 0.f;
                if (j < i)       v = acc1[jt][r] * dj * __expf(lsi[r] - lj);
                else if (j == i) v = acc1[jt][r] * dj + Dsk;
                int pc = ((((j >> 3) ^ (i & 7)) << 3) | (j & 7));
                Ssh[i * 64 + pc] = f2h(v);
            }
        }
    }
    __syncthreads();

    // --- P2: Y = S'.X ---
    f32x4_t acc2[4];
#pragma unroll
    for (int nt = 0; nt < 4; ++nt) acc2[nt] = vzero;
    {
        int ia = w * 16 + l16;
#pragma unroll
        for (int ks = 0; ks < 2; ++ks) {
            half8_t a = *(const half8_t*)&Ssh[ia * 64 + (((ks * 4 + g) ^ (ia & 7)) << 3)];
#pragma unroll
            for (int nt = 0; nt < 4; ++nt) {
                int pr = nt * 16 + l16;
                half8_t bfr = *(const half8_t*)&Xt[pr * 64 + (((ks * 4 + g) ^ (pr & 7)) << 3)];
                acc2[nt] = __builtin_amdgcn_mfma_f32_16x16x32_f16(a, bfr, acc2[nt], 0, 0, 0);
            }
        }
    }
    {
        int i0 = w * 16 + g * 4;
#pragma unroll
        for (int nt = 0; nt < 4; ++nt) {
            int p = nt * 16 + l16;
#pragma unroll
            for (int r = 0; r < 4; ++r)
                y[(rowbase + i0 + r) * D_INNER + h * 64 + p] = acc2[nt][r];
        }
    }
    // --- P3: H_local^T[p][n] = (csc-scaled Xt) . Bt ---
    f32x4_t acc3[8];
#pragma unroll
    for (int nt = 0; nt < 8; ++nt) acc3[nt] = vzero;
    {
        int pa = w * 16 + l16;
#pragma unroll
        for (int ks = 0; ks < 2; ++ks) {
            half8_t araw = *(const half8_t*)&Xt[pa * 64 + (((ks * 4 + g) ^ (pa & 7)) << 3)];
            half8_t a;
#pragma unroll
            for (int e = 0; e < 8; ++e)
                a[e] = (_Float16)((float)araw[e] * csc[ks * 32 + g * 8 + e]);
#pragma unroll
            for (int nt = 0; nt < 8; ++nt) {
                int nr = nt * 16 + l16;
                half8_t bfr = *(const half8_t*)&Bt[nr * 64 + (((ks * 4 + g) ^ (nr & 7)) << 3)];
                acc3[nt] = __builtin_amdgcn_mfma_f32_16x16x32_f16(a, bfr, acc3[nt], 0, 0, 0);
            }
        }
    }
    {
        int p0 = w * 16 + g * 4;
#pragma unroll
        for (int nt = 0; nt < 8; ++nt) {
            int n = nt * 16 + l16;
#pragma unroll
            for (int r = 0; r < 4; ++r)
                Hseg[((size_t)bi * 64 + p0 + r) * 128 + n] = f2h(acc3[nt][r]);
        }
    }
}

// ---------------------------------------------------------------------------
// PASS 2: sequential fixup across segments (in-place: Hseg -> Hin).
// Split n-dim across 2 blocks per bh (fully parallel in n).
// ---------------------------------------------------------------------------
__global__ __launch_bounds__(512)
void state_fixup_kernel(const float* __restrict__ alpha, us* __restrict__ Hseg)
{
    const int bh = blockIdx.x >> 1, hf = blockIdx.x & 1;
    const int t = threadIdx.x, p = t >> 3, ng = t & 7;
    const int off = hf * 64 + ng * 8;
    float carry[8];
#pragma unroll
    for (int j = 0; j < 8; ++j) carry[j] = 0.f;
    for (int seg = 0; seg < NSEG; ++seg) {
        us* hs = Hseg + (((size_t)bh * NSEG + seg) * 64 + p) * 128 + off;
        float ae = alpha[(size_t)bh * SEQ + seg * SEGLEN + SEGLEN - 1];
        float tmp[8];
#pragma unroll
        for (int q = 0; q < 2; ++q) {
            ushort4 u = *(const ushort4*)(hs + q * 4);
            tmp[q*4+0] = h2f(u.x); tmp[q*4+1] = h2f(u.y);
            tmp[q*4+2] = h2f(u.z); tmp[q*4+3] = h2f(u.w);
        }
#pragma unroll
        for (int q = 0; q < 2; ++q) {
            ushort4 o;
            o.x = f2h(carry[q*4+0]); o.y = f2h(carry[q*4+1]);
            o.z = f2h(carry[q*4+2]); o.w = f2h(carry[q*4+3]);
            *(ushort4*)(hs + q * 4) = o;
        }
#pragma unroll
        for (int j = 0; j < 8; ++j) carry[j] = fmaf(carry[j], ae, tmp[j]);
    }
}

// ---------------------------------------------------------------------------
// PASS 3 (MFMA): y += alpha_i * (C . Hin^T).  One block per (b,h,seg-1).
// ---------------------------------------------------------------------------
__global__ __launch_bounds__(256)
void correct_mfma_kernel(const us* __restrict__ xc, const float* __restrict__ alpha,
                         const us* __restrict__ Hseg, float* __restrict__ y)
{
    __shared__ __attribute__((aligned(16))) us Csh[64 * 128];
    __shared__ __attribute__((aligned(16))) us Hsh[64 * 128];
    __shared__ float als_s[64];
    const int bi = blockIdx.x;
    const int bh = bi / 7, seg = 1 + (bi % 7);
    const int b = bh >> 5, h = bh & 31;
    const int tid = threadIdx.x, lane = tid & 63, w = tid >> 6;
    const int g = lane >> 4, l16 = lane & 15;
    const int t0g = seg * SEGLEN;
    const size_t rowbase = (size_t)(b * SEQ + t0g);
    const size_t hbase = (size_t)(bh * NSEG + seg) * 64;

    {
        int rr = lane >> 4, s = lane & 15;
#pragma unroll
        for (int it = 0; it < 4; ++it) {
            int rb = w * 16 + it * 4;
            int row = rb + rr;
            int sw = (s ^ (row & 7)) * 8;
            gl2lds16(xc + (rowbase + row) * CONV_DIM + OFF_C + sw, &Csh[rb * 128]);
            gl2lds16(Hseg + (hbase + row) * 128 + sw, &Hsh[rb * 128]);
        }
    }
    if (tid < 64) als_s[tid] = alpha[(size_t)bh * SEQ + t0g + tid];
    __syncthreads();

    const f32x4_t vzero = {0.f, 0.f, 0.f, 0.f};
    f32x4_t acc[4];
#pragma unroll
    for (int nt = 0; nt < 4; ++nt) acc[nt] = vzero;
    int ia = w * 16 + l16;
#pragma unroll
    for (int ks = 0; ks < 4; ++ks) {
        half8_t a = *(const half8_t*)&Csh[ia * 128 + (((ks * 4 + g) ^ (ia & 7)) << 3)];
#pragma unroll
        for (int nt = 0; nt < 4; ++nt) {
            int pr = nt * 16 + l16;
            half8_t bfr = *(const half8_t*)&Hsh[pr * 128 + (((ks * 4 + g) ^ (pr & 7)) << 3)];
            acc[nt] = __builtin_amdgcn_mfma_f32_16x16x32_f16(a, bfr, acc[nt], 0, 0, 0);
        }
    }
    int i0 = w * 16 + g * 4;
#pragma unroll
    for (int nt = 0; nt < 4; ++nt) {
        int p = nt * 16 + l16;
#pragma unroll
        for (int r = 0; r < 4; ++r) {
            size_t idx = (rowbase + i0 + r) * D_INNER + h * 64 + p;
            y[idx] += als_s[i0 + r] * acc[nt][r];
        }
    }
}

// ---------------------------------------------------------------------------
// gated RMSNorm: y fp32 + z fp16 -> yn fp16.  Wave-level shfl reduce +
// single 4-slot LDS combine (1 barrier instead of 8).
// ---------------------------------------------------------------------------
__global__ __launch_bounds__(256)
void gated_rmsnorm_kernel(const float* __restrict__ y,
                          const us* __restrict__ zxbcdt,
                          const float* __restrict__ norm_w,
                          us* __restrict__ yn)
{
    int bl = blockIdx.x;
    int t  = threadIdx.x;
    const float* yr = y + (size_t)bl * D_INNER;
    const us* zr = zxbcdt + (size_t)bl * D_IN_PROJ;
    us* outr = yn + (size_t)bl * D_INNER;

    float gv[8];
    float ss = 0.f;
#pragma unroll
    for (int q = 0; q < 8; ++q) {
        int j = t + q * 256;
        float z = h2f(zr[j]);
        float g = yr[j] * (z / (1.f + __expf(-z)));
        gv[q] = g;
        ss += g * g;
    }
#pragma unroll
    for (int o = 32; o > 0; o >>= 1) ss += __shfl_down(ss, o);
    __shared__ float red[4];
    if ((t & 63) == 0) red[t >> 6] = ss;
    __syncthreads();
    float tot = red[0] + red[1] + red[2] + red[3];
    float rs = rsqrtf(tot / (float)D_INNER + 1e-5f);
#pragma unroll
    for (int q = 0; q < 8; ++q) {
        int j = t + q * 256;
        outr[j] = f2h(gv[q] * rs * norm_w[j]);
    }
}

// ---------------------------------------------------------------------------
// final: out[tok] = dot(t1[tok,:], w2[:,0]) + b2   (t1 fp16)
// ---------------------------------------------------------------------------
__global__ __launch_bounds__(256)
void final_dot_kernel(const us* __restrict__ t1,
                      const float* __restrict__ w2,
                      const float* __restrict__ b2,
                      float* __restrict__ out)
{
    int bl = blockIdx.x;
    int t  = threadIdx.x;
    float s = 0.f;
    for (int j = t; j < D_MODEL; j += 256)
        s = fmaf(h2f(t1[(size_t)bl * D_MODEL + j]), w2[j], s);
#pragma unroll
    for (int o = 32; o > 0; o >>= 1) s += __shfl_down(s, o);
    __shared__ float red[4];
    if ((t & 63) == 0) red[t >> 6] = s;
    __syncthreads();
    if (t == 0) out[bl] = red[0] + red[1] + red[2] + red[3] + b2[0];
}

// ---------------------------------------------------------------------------
extern "C" void kernel_launch(void* const* d_in, const int* in_sizes, int n_in,
                              void* d_out, int out_size, void* d_ws, size_t ws_size,
                              hipStream_t stream)
{
    const float* x        = (const float*)d_in[0];
    const float* steps    = (const float*)d_in[1];
    const float* curr     = (const float*)d_in[2];
    const float* mi_w1    = (const float*)d_in[3];
    const float* mi_b1    = (const float*)d_in[4];
    const float* mi_w2    = (const float*)d_in[5];
    const float* mi_b2    = (const float*)d_in[6];
    const float* W_in     = (const float*)d_in[7];
    const float* conv_w   = (const float*)d_in[8];
    const float* conv_b   = (const float*)d_in[9];
    const float* dt_bias  = (const float*)d_in[10];
    const float* A_log    = (const float*)d_in[11];
    const float* D_skip   = (const float*)d_in[12];
    const float* norm_w   = (const float*)d_in[13];
    const float* W_out    = (const float*)d_in[14];
    const float* mo_w1    = (const float*)d_in[15];
    const float* mo_b1    = (const float*)d_in[16];
    const float* mo_w2    = (const float*)d_in[17];
    const float* mo_b2    = (const float*)d_in[18];
    float* out = (float*)d_out;

    // ---- workspace layout ----
    us* wt_mi1 = (us*)d_ws;
    us* wt_mi2 = wt_mi1 + (size_t)512 * 512;
    us* wt_in  = wt_mi2 + (size_t)1024 * 512;
    us* wt_out = wt_in  + (size_t)4 * NPAD_IN * 1024;
    us* wt_mo1 = wt_out + (size_t)4 * 1024 * 2048;
    us* Hseg   = wt_mo1 + (size_t)1024 * 1024;
    us* hcat   = Hseg   + (size_t)NBH * NSEG * 64 * 128;
    us* h      = hcat   + (size_t)NTOK * 512;
    us* zxb    = h      + (size_t)NTOK * D_MODEL;
    us* xc     = zxb    + (size_t)NTOK * D_IN_PROJ;
    us* yn     = xc     + (size_t)NTOK * CONV_DIM;
    us* t0     = zxb;
    us* t1     = xc;
    float* fbase = (float*)((((uintptr_t)(yn + (size_t)NTOK * D_INNER)) + 255)
                            & ~(uintptr_t)255);
    float* y     = fbase;
    float* alpha = y + (size_t)NTOK * D_INNER;

    // ---- all weight transposes: ONE dispatch ----
    transpose_all_kernel<<<NT_TRANS, 256, 0, stream>>>(
        mi_w1, mi_w2, W_in, W_out, mo_w1,
        wt_mi1, wt_mi2, wt_in, wt_out, wt_mo1);

    // ---- forward ----
    concat_kernel<<<(NTOK * 512 + 255) / 256, 256, 0, stream>>>(x, steps, curr, hcat);

    mfma_gemm_f16<64, 64, 1><<<dim3(512/64, NTOK/64), 256, 0, stream>>>(
        hcat, wt_mi1, mi_b1, t0, 512, 512, 1);
    mfma_gemm_f16<64, 64, 1><<<dim3(1024/64, NTOK/64), 256, 0, stream>>>(
        t0, wt_mi2, mi_b2, h, 1024, 512, 0);

    for (int i = 0; i < NBLOCKS; ++i) {
        mfma_gemm_f16<128, 128, 4><<<dim3(NPAD_IN/128, NTOK/128), 256, 0, stream>>>(
            h, wt_in + (size_t)i * NPAD_IN * 1024, nullptr, zxb, D_IN_PROJ, D_MODEL, 0);
        conv_silu_kernel<<<(NTOK * (CONV_DIM/8) + 255) / 256, 256, 0, stream>>>(
            zxb, conv_w + (size_t)i * CONV_DIM * DCONV, conv_b + (size_t)i * CONV_DIM, xc);
        scan_seg_mfma_kernel<<<NBH * NSEG, 256, 0, stream>>>(
            zxb, xc, dt_bias + i * NHEADS, A_log + i * NHEADS, D_skip + i * NHEADS,
            y, alpha, Hseg);
        state_fixup_kernel<<<NBH * 2, 512, 0, stream>>>(alpha, Hseg);
        correct_mfma_kernel<<<NBH * (NSEG - 1), 256, 0, stream>>>(xc, alpha, Hseg, y);
        gated_rmsnorm_kernel<<<NTOK, 256, 0, stream>>>(
            y, zxb, norm_w + (size_t)i * D_INNER, yn);
        mfma_gemm_f16<64, 64, 1><<<dim3(1024/64, NTOK/64), 256, 0, stream>>>(
            yn, wt_out + (size_t)i * 1024 * 2048, nullptr, h, 1024, 2048, 0);
    }

    mfma_gemm_f16<64, 64, 1><<<dim3(1024/64, NTOK/64), 256, 0, stream>>>(
        h, wt_mo1, mo_b1, t1, 1024, 1024, 1);
    final_dot_kernel<<<NTOK, 256, 0, stream>>>(t1, mo_w2, mo_b2, out);
}

// Round 13
// 720.336 us; speedup vs baseline: 1.1081x; 1.1081x over previous
//
#include <hip/hip_runtime.h>
#include <hip/hip_bf16.h>
#include <math.h>

#define D_MODEL   1024
#define D_INNER   2048
#define D_STATE   128
#define NHEADS    32
#define HEADDIM   64
#define DCONV     4
#define CONV_DIM  (D_INNER + 2 * D_STATE)              // 2304
#define D_IN_PROJ (2 * D_INNER + 2 * D_STATE + NHEADS) // 4384
#define NBLOCKS   4
#define BATCH     4
#define SEQ       512
#define NTOK      (BATCH * SEQ)                        // 2048
#define STATE_IN  510
#define NPAD_IN   4480
#define NSEG      8
#define SEGLEN    64
#define NBH       (BATCH * NHEADS)                     // 128
#define OFF_B     D_INNER                              // 2048
#define OFF_C     (D_INNER + D_STATE)                  // 2176
#define OFF_DT    (D_IN_PROJ - NHEADS)

typedef _Float16 half8_t __attribute__((ext_vector_type(8)));
typedef float f32x4_t  __attribute__((ext_vector_type(4)));
typedef unsigned short us;
typedef unsigned short us8 __attribute__((ext_vector_type(8)));

__device__ __forceinline__ us f2h(float f) {
    _Float16 h = (_Float16)f;
    return __builtin_bit_cast(us, h);
}
__device__ __forceinline__ float h2f(us u) {
    return (float)__builtin_bit_cast(_Float16, u);
}
__device__ __forceinline__ void gl2lds16(const us* gp, us* lp) {
    __builtin_amdgcn_global_load_lds(
        (const __attribute__((address_space(1))) unsigned int*)(gp),
        (__attribute__((address_space(3))) unsigned int*)(lp), 16, 0, 0);
}

// ---------------------------------------------------------------------------
// concat -> hcat [NTOK, 512] fp16
// ---------------------------------------------------------------------------
__global__ void concat_kernel(const float* __restrict__ x,
                              const float* __restrict__ steps,
                              const float* __restrict__ curr,
                              us* __restrict__ hcat)
{
    int idx = blockIdx.x * 256 + threadIdx.x;
    if (idx >= NTOK * 512) return;
    int bl = idx >> 9;
    int c  = idx & 511;
    float v;
    if (c < STATE_IN)       v = x[(size_t)bl * STATE_IN + c];
    else if (c == STATE_IN) v = steps[bl];
    else                    v = curr[bl];
    hcat[idx] = f2h(v);
}

// ---------------------------------------------------------------------------
// ALL weight transposes, ONE dispatch, REGISTERS ONLY (no LDS, no barrier).
// Each thread transposes an 8k x 4n micro-tile: 8 independent float4 loads,
// 4 x 16B us8 stores where 8 consecutive lanes form a 128 B contiguous chunk.
// Block tile: 64k x 128n.  W[K,N] fp32 -> WT[Npad,K] fp16.  Tile ranges:
//   [0,32)       mi_w1   K=512  N=512   ntx=4
//   [32,96)      mi_w2   K=512  N=1024  ntx=8
//   [96,2336)    W_in i  K=1024 N=4384  ntx=35 (pad to 4480: zero-fill)
//   [2336,3360)  W_out i K=2048 N=1024  ntx=8
//   [3360,3488)  mo_w1   K=1024 N=1024  ntx=8
// ---------------------------------------------------------------------------
#define NT_TRANS 3488
__global__ __launch_bounds__(256)
void transpose_all_kernel(const float* __restrict__ mi_w1, const float* __restrict__ mi_w2,
                          const float* __restrict__ W_in, const float* __restrict__ W_out,
                          const float* __restrict__ mo_w1,
                          us* __restrict__ wt_mi1, us* __restrict__ wt_mi2,
                          us* __restrict__ wt_in, us* __restrict__ wt_out,
                          us* __restrict__ wt_mo1)
{
    int bid = blockIdx.x;
    const float* W; us* WT; int K, N, ntx, r;
    if (bid < 32)        { W = mi_w1; WT = wt_mi1; K = 512;  N = 512;  ntx = 4; r = bid; }
    else if (bid < 96)   { W = mi_w2; WT = wt_mi2; K = 512;  N = 1024; ntx = 8; r = bid - 32; }
    else if (bid < 2336) {
        int rel = bid - 96, i = rel / 560;
        r = rel - i * 560;
        W  = W_in  + (size_t)i * D_MODEL * D_IN_PROJ;
        WT = wt_in + (size_t)i * NPAD_IN * 1024;
        K = 1024; N = D_IN_PROJ; ntx = 35;
    }
    else if (bid < 3360) {
        int rel = bid - 2336, i = rel / 256;
        r = rel - i * 256;
        W  = W_out  + (size_t)i * D_INNER * D_MODEL;
        WT = wt_out + (size_t)i * 1024 * 2048;
        K = 2048; N = 1024; ntx = 8;
    }
    else { W = mo_w1; WT = wt_mo1; K = 1024; N = 1024; ntx = 8; r = bid - 3360; }
    int n0 = (r % ntx) * 128, k0 = (r / ntx) * 64;

    int t = threadIdx.x;
    int ko = t & 7;            // k-octet within 64-row tile
    int nq = t >> 3;           // n-quad within 128-col tile (0..31)
    int n  = n0 + nq * 4;
    int k  = k0 + ko * 8;

    float4 v[8];
    if (n < N) {
        const float* src = W + (size_t)k * N + n;
#pragma unroll
        for (int j = 0; j < 8; ++j)
            v[j] = *(const float4*)(src + (size_t)j * N);
    } else {
#pragma unroll
        for (int j = 0; j < 8; ++j) v[j] = make_float4(0.f, 0.f, 0.f, 0.f);
    }
#pragma unroll
    for (int q = 0; q < 4; ++q) {
        us8 o;
#pragma unroll
        for (int j = 0; j < 8; ++j) o[j] = f2h(((const float*)&v[j])[q]);
        *(us8*)(WT + (size_t)(n + q) * K + k) = o;
    }
}

// ---------------------------------------------------------------------------
// fp16 MFMA GEMM, triple-buffered K-pipeline, UNROLLED x3 (static LDS bases).
// body(t): wait vmcnt(L) -> s_barrier -> stage(t+2) -> compute(t)
// L = loads/tile/wave = BM/64 + BN/64; steady-state wait = vmcnt(L).
// XCD-aware block swizzle (T1).
// ---------------------------------------------------------------------------
#define PHASE(TT, CUR, STG)                                                     \
    {                                                                           \
        if ((TT) == NT - 1)                                                     \
            asm volatile("s_waitcnt vmcnt(0)" ::: "memory");                    \
        else if constexpr (BM / 64 + BN / 64 == 4)                              \
            asm volatile("s_waitcnt vmcnt(4)" ::: "memory");                    \
        else if constexpr (BM / 64 + BN / 64 == 3)                              \
            asm volatile("s_waitcnt vmcnt(3)" ::: "memory");                    \
        else                                                                    \
            asm volatile("s_waitcnt vmcnt(2)" ::: "memory");                    \
        __builtin_amdgcn_s_barrier();                                           \
        if ((TT) + 2 < NT) stage(STG, ((TT) + 2) << 5);                         \
        half8_t af[TI], bfr[4];                                                 \
        _Pragma("unroll")                                                       \
        for (int ti = 0; ti < TI; ++ti) {                                       \
            int rr = wr + ti * 16 + l16;                                        \
            af[ti] = *(const half8_t*)&Al[CUR][rr * 32 + ((g ^ ((rr >> 2) & 3)) * 8)]; \
        }                                                                       \
        _Pragma("unroll")                                                       \
        for (int tj = 0; tj < 4; ++tj) {                                        \
            int rr = wc + tj * 16 + l16;                                        \
            bfr[tj] = *(const half8_t*)&Bl[CUR][rr * 32 + ((g ^ ((rr >> 2) & 3)) * 8)]; \
        }                                                                       \
        _Pragma("unroll")                                                       \
        for (int ti = 0; ti < TI; ++ti)                                         \
            _Pragma("unroll")                                                   \
            for (int tj = 0; tj < 4; ++tj)                                      \
                acc[ti][tj] = __builtin_amdgcn_mfma_f32_16x16x32_f16(           \
                    af[ti], bfr[tj], acc[ti][tj], 0, 0, 0);                     \
    }

template<int BM, int BN, int TI>
__global__ __launch_bounds__(256)
void mfma_gemm_f16(const us* __restrict__ A, const us* __restrict__ BT,
                   const float* __restrict__ bias, us* __restrict__ C,
                   int N, int K, int relu)
{
    __shared__ __attribute__((aligned(16))) us Al[3][BM * 32];
    __shared__ __attribute__((aligned(16))) us Bl[3][BN * 32];
    const int tid = threadIdx.x, lane = tid & 63, wave = tid >> 6;
    const int g = lane >> 4, l16 = lane & 15;
    const int wr = (BN == 128) ? (wave >> 1) * 64 : wave * (BM / 4);
    const int wc = (BN == 128) ? (wave & 1) * 64 : 0;

    // XCD-aware swizzle (bijective when nwg % 8 == 0; identity otherwise)
    int bx = blockIdx.x, by = blockIdx.y;
    {
        int nbx = gridDim.x;
        int nwg = nbx * gridDim.y;
        if (!(nwg & 7)) {
            int id  = by * nbx + bx;
            int swz = (id & 7) * (nwg >> 3) + (id >> 3);
            bx = swz % nbx;
            by = swz / nbx;
        }
    }
    const int m0 = by * BM, n0 = bx * BN;
    const int lrow = lane >> 2;
    const int lcol = ((lane & 3) ^ ((lrow >> 2) & 3)) * 8;

    f32x4_t acc[TI][4];
    const f32x4_t zero = {0.f, 0.f, 0.f, 0.f};
#pragma unroll
    for (int i = 0; i < TI; ++i)
#pragma unroll
        for (int j = 0; j < 4; ++j) acc[i][j] = zero;

    const us* abase = A  + (size_t)m0 * K;
    const us* bbase = BT + (size_t)n0 * K;

    auto stage = [&](int buf, int k0) {
#pragma unroll
        for (int s = 0; s < BM / 64; ++s) {
            int rb = wave * (BM / 4) + s * 16;
            gl2lds16(abase + (size_t)(rb + lrow) * K + k0 + lcol, &Al[buf][rb * 32]);
        }
#pragma unroll
        for (int s = 0; s < BN / 64; ++s) {
            int rb = wave * (BN / 4) + s * 16;
            gl2lds16(bbase + (size_t)(rb + lrow) * K + k0 + lcol, &Bl[buf][rb * 32]);
        }
    };

    const int NT = K >> 5;
    stage(0, 0);
    stage(1, 32);

    for (int t = 0; t < NT; t += 3) {
        PHASE(t, 0, 2)
        if (t + 1 < NT) PHASE(t + 1, 1, 0)
        if (t + 2 < NT) PHASE(t + 2, 2, 1)
    }

#pragma unroll
    for (int tj = 0; tj < 4; ++tj) {
        int col = n0 + wc + tj * 16 + l16;
        if (col >= N) continue;
        float bv = bias ? bias[col] : 0.f;
#pragma unroll
        for (int ti = 0; ti < TI; ++ti) {
            int rbase = m0 + wr + ti * 16 + g * 4;
#pragma unroll
            for (int r = 0; r < 4; ++r) {
                float v = acc[ti][tj][r] + bv;
                if (relu) v = fmaxf(v, 0.f);
                C[(size_t)(rbase + r) * N + col] = f2h(v);
            }
        }
    }
}

// ---------------------------------------------------------------------------
// causal depthwise conv1d (k=4) + SiLU; vectorized 4 channels/thread
// (float4 conv-weight loads per channel — coalesced & fewest instructions)
// ---------------------------------------------------------------------------
__global__ __launch_bounds__(256)
void conv_silu_kernel(const us* __restrict__ zxbcdt,
                      const float* __restrict__ cw,
                      const float* __restrict__ cb,
                      us* __restrict__ xBCc)
{
    int idx = blockIdx.x * 256 + threadIdx.x;          // quad index
    if (idx >= NTOK * (CONV_DIM / 4)) return;
    int cq = idx % (CONV_DIM / 4);
    int bl = idx / (CONV_DIM / 4);
    int b  = bl >> 9;
    int l  = bl & 511;
    int c  = cq * 4;
    float4 w0 = *(const float4*)&cw[(c + 0) * DCONV];
    float4 w1 = *(const float4*)&cw[(c + 1) * DCONV];
    float4 w2 = *(const float4*)&cw[(c + 2) * DCONV];
    float4 w3 = *(const float4*)&cw[(c + 3) * DCONV];
    float4 bb = *(const float4*)&cb[c];
    float a0 = bb.x, a1 = bb.y, a2 = bb.z, a3 = bb.w;
    const us* base = zxbcdt + (size_t)(b * SEQ) * D_IN_PROJ + D_INNER + c;
#pragma unroll
    for (int k = 0; k < DCONV; ++k) {
        int ll = l + k - (DCONV - 1);
        if (ll >= 0) {
            ushort4 u = *(const ushort4*)(base + (size_t)ll * D_IN_PROJ);
            a0 = fmaf(h2f(u.x), ((const float*)&w0)[k], a0);
            a1 = fmaf(h2f(u.y), ((const float*)&w1)[k], a1);
            a2 = fmaf(h2f(u.z), ((const float*)&w2)[k], a2);
            a3 = fmaf(h2f(u.w), ((const float*)&w3)[k], a3);
        }
    }
    ushort4 o;
    o.x = f2h(a0 / (1.f + __expf(-a0)));
    o.y = f2h(a1 / (1.f + __expf(-a1)));
    o.z = f2h(a2 / (1.f + __expf(-a2)));
    o.w = f2h(a3 / (1.f + __expf(-a3)));
    *(ushort4*)(xBCc + (size_t)bl * CONV_DIM + c) = o;
}

// ---------------------------------------------------------------------------
// PASS 1 (MFMA chunked SSD): one block per (b,h,seg); 256 threads = 4 waves.
// ---------------------------------------------------------------------------
__global__ __launch_bounds__(256)
void scan_seg_mfma_kernel(const us* __restrict__ zx, const us* __restrict__ xc,
                          const float* __restrict__ dt_bias,
                          const float* __restrict__ A_log,
                          const float* __restrict__ D_skip,
                          float* __restrict__ y, float* __restrict__ alpha,
                          us* __restrict__ Hseg)
{
    __shared__ __attribute__((aligned(16))) us Csh[64 * 128];  // P1 A; aliased by Ssh
    __shared__ __attribute__((aligned(16))) us Bsh[64 * 128];  // P1 B
    __shared__ __attribute__((aligned(16))) us Bt[128 * 64];   // B^T [n][j], P3
    __shared__ __attribute__((aligned(16))) us Xt[64 * 64];    // X^T [p][j], P2/P3
    __shared__ float dt_s[64], ls[64], csc[64];
    us* Ssh = Csh;                                             // S' [i][j] (8 KB of 16)
    const int bi = blockIdx.x, bh = bi >> 3, seg = bi & 7;
    const int b = bh >> 5, h = bh & 31;
    const int tid = threadIdx.x, lane = tid & 63, w = tid >> 6;
    const int g = lane >> 4, l16 = lane & 15;
    const int t0g = seg * SEGLEN;
    const size_t rowbase = (size_t)(b * SEQ + t0g);

    // --- async DMA staging of C and B tiles (row-major, swizzled) ---
    {
        int rr = lane >> 4, s = lane & 15;
#pragma unroll
        for (int it = 0; it < 4; ++it) {
            int rb = w * 16 + it * 4;
            int row = rb + rr;
            const us* src = xc + (rowbase + row) * CONV_DIM;
            int sw = (s ^ (row & 7)) * 8;
            gl2lds16(src + OFF_C + sw, &Csh[rb * 128]);
            gl2lds16(src + OFF_B + sw, &Bsh[rb * 128]);
        }
    }
    // --- VGPR transpose staging: Xt[p][j] ---
#pragma unroll
    for (int qi = 0; qi < 4; ++qi) {
        int idx = tid + qi * 256;          // 1024 quads
        int pq = idx & 15, j = idx >> 4;
        ushort4 v = *(const ushort4*)(xc + (rowbase + j) * CONV_DIM + h * 64 + pq * 4);
#pragma unroll
        for (int e = 0; e < 4; ++e) {
            int p = pq * 4 + e;
            int pc = ((((j >> 3) ^ (p & 7)) << 3) | (j & 7));
            Xt[p * 64 + pc] = ((const us*)&v)[e];
        }
    }
    // --- VGPR transpose staging: Bt[n][j] ---
#pragma unroll
    for (int qi = 0; qi < 8; ++qi) {
        int idx = tid + qi * 256;          // 2048 quads
        int nq = idx & 31, j = idx >> 5;
        ushort4 v = *(const ushort4*)(xc + (rowbase + j) * CONV_DIM + OFF_B + nq * 4);
#pragma unroll
        for (int e = 0; e < 4; ++e) {
            int n = nq * 4 + e;
            int pc = ((((j >> 3) ^ (n & 7)) << 3) | (j & 7));
            Bt[n * 64 + pc] = ((const us*)&v)[e];
        }
    }
    // --- dt / cumulative decay (wave 0) ---
    if (tid < 64) {
        int j = tid;
        float dtraw = h2f(zx[(rowbase + j) * D_IN_PROJ + OFF_DT + h]) + dt_bias[h];
        float dtv = (dtraw > 20.f) ? dtraw : log1pf(expf(dtraw));
        float ld = dtv * (-expf(A_log[h]));
#pragma unroll
        for (int o = 1; o < 64; o <<= 1) {
            float v = __shfl_up(ld, o);
            if (j >= o) ld += v;
        }
        float al = expf(ld);
        dt_s[j] = dtv;
        ls[j] = ld;
        alpha[(size_t)bh * SEQ + t0g + j] = al;
        float cend = __shfl(ld, 63);
        csc[j] = dtv * expf(cend - ld);
    }
    __syncthreads();   // DMA drained (vmcnt0 before barrier) + stagings visible

    const float Dsk = D_skip[h];
    const f32x4_t vzero = {0.f, 0.f, 0.f, 0.f};

    // --- P1: G = C.B^T ---
    f32x4_t acc1[4];
#pragma unroll
    for (int jt = 0; jt < 4; ++jt) acc1[jt] = vzero;
    {
        int ia = w * 16 + l16;
#pragma unroll
        for (int ks = 0; ks < 4; ++ks) {
            half8_t a = *(const half8_t*)&Csh[ia * 128 + (((ks * 4 + g) ^ (ia & 7)) << 3)];
#pragma unroll
            for (int jt = 0; jt < 4; ++jt) {
                int jr = jt * 16 + l16;
                half8_t bfr = *(const half8_t*)&Bsh[jr * 128 + (((ks * 4 + g) ^ (jr & 7)) << 3)];
                acc1[jt] = __builtin_amdgcn_mfma_f32_16x16x32_f16(a, bfr, acc1[jt], 0, 0, 0);
            }
        }
    }
    __syncthreads();   // all waves done reading Csh before Ssh overwrites it

    // --- S' mask/scale -> Ssh (aliases Csh) ---
    {
        int i0 = w * 16 + g * 4;
        float lsi[4];
#pragma unroll
        for (int r = 0; r < 4; ++r) lsi[r] = ls[i0 + r];
#pragma unroll
        for (int jt = 0; jt < 4; ++jt) {
            int j = jt * 16 + l16;
            float lj = ls[j], dj = dt_s[j];
#pragma unroll
            for (int r = 0; r < 4; ++r) {
                int i = i0 + r;
                float v = 0.f;
                if (j < i)       v = acc1[jt][r] * dj * __expf(lsi[r] - lj);
                else if (j == i) v = acc1[jt][r] * dj + Dsk;
                int pc = ((((j >> 3) ^ (i & 7)) << 3) | (j & 7));
                Ssh[i * 64 + pc] = f2h(v);
            }
        }
    }
    __syncthreads();

    // --- P2: Y = S'.X ---
    f32x4_t acc2[4];
#pragma unroll
    for (int nt = 0; nt < 4; ++nt) acc2[nt] = vzero;
    {
        int ia = w * 16 + l16;
#pragma unroll
        for (int ks = 0; ks < 2; ++ks) {
            half8_t a = *(const half8_t*)&Ssh[ia * 64 + (((ks * 4 + g) ^ (ia & 7)) << 3)];
#pragma unroll
            for (int nt = 0; nt < 4; ++nt) {
                int pr = nt * 16 + l16;
                half8_t bfr = *(const half8_t*)&Xt[pr * 64 + (((ks * 4 + g) ^ (pr & 7)) << 3)];
                acc2[nt] = __builtin_amdgcn_mfma_f32_16x16x32_f16(a, bfr, acc2[nt], 0, 0, 0);
            }
        }
    }
    {
        int i0 = w * 16 + g * 4;
#pragma unroll
        for (int nt = 0; nt < 4; ++nt) {
            int p = nt * 16 + l16;
#pragma unroll
            for (int r = 0; r < 4; ++r)
                y[(rowbase + i0 + r) * D_INNER + h * 64 + p] = acc2[nt][r];
        }
    }
    // --- P3: H_local^T[p][n] = (csc-scaled Xt) . Bt ---
    f32x4_t acc3[8];
#pragma unroll
    for (int nt = 0; nt < 8; ++nt) acc3[nt] = vzero;
    {
        int pa = w * 16 + l16;
#pragma unroll
        for (int ks = 0; ks < 2; ++ks) {
            half8_t araw = *(const half8_t*)&Xt[pa * 64 + (((ks * 4 + g) ^ (pa & 7)) << 3)];
            half8_t a;
#pragma unroll
            for (int e = 0; e < 8; ++e)
                a[e] = (_Float16)((float)araw[e] * csc[ks * 32 + g * 8 + e]);
#pragma unroll
            for (int nt = 0; nt < 8; ++nt) {
                int nr = nt * 16 + l16;
                half8_t bfr = *(const half8_t*)&Bt[nr * 64 + (((ks * 4 + g) ^ (nr & 7)) << 3)];
                acc3[nt] = __builtin_amdgcn_mfma_f32_16x16x32_f16(a, bfr, acc3[nt], 0, 0, 0);
            }
        }
    }
    {
        int p0 = w * 16 + g * 4;
#pragma unroll
        for (int nt = 0; nt < 8; ++nt) {
            int n = nt * 16 + l16;
#pragma unroll
            for (int r = 0; r < 4; ++r)
                Hseg[((size_t)bi * 64 + p0 + r) * 128 + n] = f2h(acc3[nt][r]);
        }
    }
}

// ---------------------------------------------------------------------------
// PASS 2: sequential fixup across segments (in-place: Hseg -> Hin).
// Split n-dim across 2 blocks per bh (fully parallel in n).
// ---------------------------------------------------------------------------
__global__ __launch_bounds__(512)
void state_fixup_kernel(const float* __restrict__ alpha, us* __restrict__ Hseg)
{
    const int bh = blockIdx.x >> 1, hf = blockIdx.x & 1;
    const int t = threadIdx.x, p = t >> 3, ng = t & 7;
    const int off = hf * 64 + ng * 8;
    float carry[8];
#pragma unroll
    for (int j = 0; j < 8; ++j) carry[j] = 0.f;
    for (int seg = 0; seg < NSEG; ++seg) {
        us* hs = Hseg + (((size_t)bh * NSEG + seg) * 64 + p) * 128 + off;
        float ae = alpha[(size_t)bh * SEQ + seg * SEGLEN + SEGLEN - 1];
        float tmp[8];
#pragma unroll
        for (int q = 0; q < 2; ++q) {
            ushort4 u = *(const ushort4*)(hs + q * 4);
            tmp[q*4+0] = h2f(u.x); tmp[q*4+1] = h2f(u.y);
            tmp[q*4+2] = h2f(u.z); tmp[q*4+3] = h2f(u.w);
        }
#pragma unroll
        for (int q = 0; q < 2; ++q) {
            ushort4 o;
            o.x = f2h(carry[q*4+0]); o.y = f2h(carry[q*4+1]);
            o.z = f2h(carry[q*4+2]); o.w = f2h(carry[q*4+3]);
            *(ushort4*)(hs + q * 4) = o;
        }
#pragma unroll
        for (int j = 0; j < 8; ++j) carry[j] = fmaf(carry[j], ae, tmp[j]);
    }
}

// ---------------------------------------------------------------------------
// PASS 3 (MFMA): y += alpha_i * (C . Hin^T).  One block per (b,h,seg-1).
// ---------------------------------------------------------------------------
__global__ __launch_bounds__(256)
void correct_mfma_kernel(const us* __restrict__ xc, const float* __restrict__ alpha,
                         const us* __restrict__ Hseg, float* __restrict__ y)
{
    __shared__ __attribute__((aligned(16))) us Csh[64 * 128];
    __shared__ __attribute__((aligned(16))) us Hsh[64 * 128];
    __shared__ float als_s[64];
    const int bi = blockIdx.x;
    const int bh = bi / 7, seg = 1 + (bi % 7);
    const int b = bh >> 5, h = bh & 31;
    const int tid = threadIdx.x, lane = tid & 63, w = tid >> 6;
    const int g = lane >> 4, l16 = lane & 15;
    const int t0g = seg * SEGLEN;
    const size_t rowbase = (size_t)(b * SEQ + t0g);
    const size_t hbase = (size_t)(bh * NSEG + seg) * 64;

    {
        int rr = lane >> 4, s = lane & 15;
#pragma unroll
        for (int it = 0; it < 4; ++it) {
            int rb = w * 16 + it * 4;
            int row = rb + rr;
            int sw = (s ^ (row & 7)) * 8;
            gl2lds16(xc + (rowbase + row) * CONV_DIM + OFF_C + sw, &Csh[rb * 128]);
            gl2lds16(Hseg + (hbase + row) * 128 + sw, &Hsh[rb * 128]);
        }
    }
    if (tid < 64) als_s[tid] = alpha[(size_t)bh * SEQ + t0g + tid];
    __syncthreads();

    const f32x4_t vzero = {0.f, 0.f, 0.f, 0.f};
    f32x4_t acc[4];
#pragma unroll
    for (int nt = 0; nt < 4; ++nt) acc[nt] = vzero;
    int ia = w * 16 + l16;
#pragma unroll
    for (int ks = 0; ks < 4; ++ks) {
        half8_t a = *(const half8_t*)&Csh[ia * 128 + (((ks * 4 + g) ^ (ia & 7)) << 3)];
#pragma unroll
        for (int nt = 0; nt < 4; ++nt) {
            int pr = nt * 16 + l16;
            half8_t bfr = *(const half8_t*)&Hsh[pr * 128 + (((ks * 4 + g) ^ (pr & 7)) << 3)];
            acc[nt] = __builtin_amdgcn_mfma_f32_16x16x32_f16(a, bfr, acc[nt], 0, 0, 0);
        }
    }
    int i0 = w * 16 + g * 4;
#pragma unroll
    for (int nt = 0; nt < 4; ++nt) {
        int p = nt * 16 + l16;
#pragma unroll
        for (int r = 0; r < 4; ++r) {
            size_t idx = (rowbase + i0 + r) * D_INNER + h * 64 + p;
            y[idx] += als_s[i0 + r] * acc[nt][r];
        }
    }
}

// ---------------------------------------------------------------------------
// gated RMSNorm: y fp32 + z fp16 -> yn fp16
// ---------------------------------------------------------------------------
__global__ __launch_bounds__(256)
void gated_rmsnorm_kernel(const float* __restrict__ y,
                          const us* __restrict__ zxbcdt,
                          const float* __restrict__ norm_w,
                          us* __restrict__ yn)
{
    int bl = blockIdx.x;
    int t  = threadIdx.x;
    const float* yr = y + (size_t)bl * D_INNER;
    const us* zr = zxbcdt + (size_t)bl * D_IN_PROJ;
    us* outr = yn + (size_t)bl * D_INNER;

    float gv[8];
    float ss = 0.f;
#pragma unroll
    for (int q = 0; q < 8; ++q) {
        int j = t + q * 256;
        float z = h2f(zr[j]);
        float g = yr[j] * (z / (1.f + __expf(-z)));
        gv[q] = g;
        ss += g * g;
    }
    __shared__ float red[256];
    red[t] = ss;
    __syncthreads();
    for (int w = 128; w > 0; w >>= 1) {
        if (t < w) red[t] += red[t + w];
        __syncthreads();
    }
    float rs = rsqrtf(red[0] / (float)D_INNER + 1e-5f);
#pragma unroll
    for (int q = 0; q < 8; ++q) {
        int j = t + q * 256;
        outr[j] = f2h(gv[q] * rs * norm_w[j]);
    }
}

// ---------------------------------------------------------------------------
// final: out[tok] = dot(t1[tok,:], w2[:,0]) + b2   (t1 fp16)
// ---------------------------------------------------------------------------
__global__ __launch_bounds__(256)
void final_dot_kernel(const us* __restrict__ t1,
                      const float* __restrict__ w2,
                      const float* __restrict__ b2,
                      float* __restrict__ out)
{
    int bl = blockIdx.x;
    int t  = threadIdx.x;
    float s = 0.f;
    for (int j = t; j < D_MODEL; j += 256)
        s = fmaf(h2f(t1[(size_t)bl * D_MODEL + j]), w2[j], s);
    __shared__ float red[256];
    red[t] = s;
    __syncthreads();
    for (int w = 128; w > 0; w >>= 1) {
        if (t < w) red[t] += red[t + w];
        __syncthreads();
    }
    if (t == 0) out[bl] = red[0] + b2[0];
}

// ---------------------------------------------------------------------------
extern "C" void kernel_launch(void* const* d_in, const int* in_sizes, int n_in,
                              void* d_out, int out_size, void* d_ws, size_t ws_size,
                              hipStream_t stream)
{
    const float* x        = (const float*)d_in[0];
    const float* steps    = (const float*)d_in[1];
    const float* curr     = (const float*)d_in[2];
    const float* mi_w1    = (const float*)d_in[3];
    const float* mi_b1    = (const float*)d_in[4];
    const float* mi_w2    = (const float*)d_in[5];
    const float* mi_b2    = (const float*)d_in[6];
    const float* W_in     = (const float*)d_in[7];
    const float* conv_w   = (const float*)d_in[8];
    const float* conv_b   = (const float*)d_in[9];
    const float* dt_bias  = (const float*)d_in[10];
    const float* A_log    = (const float*)d_in[11];
    const float* D_skip   = (const float*)d_in[12];
    const float* norm_w   = (const float*)d_in[13];
    const float* W_out    = (const float*)d_in[14];
    const float* mo_w1    = (const float*)d_in[15];
    const float* mo_b1    = (const float*)d_in[16];
    const float* mo_w2    = (const float*)d_in[17];
    const float* mo_b2    = (const float*)d_in[18];
    float* out = (float*)d_out;

    // ---- workspace layout ----
    us* wt_mi1 = (us*)d_ws;
    us* wt_mi2 = wt_mi1 + (size_t)512 * 512;
    us* wt_in  = wt_mi2 + (size_t)1024 * 512;
    us* wt_out = wt_in  + (size_t)4 * NPAD_IN * 1024;
    us* wt_mo1 = wt_out + (size_t)4 * 1024 * 2048;
    us* Hseg   = wt_mo1 + (size_t)1024 * 1024;
    us* hcat   = Hseg   + (size_t)NBH * NSEG * 64 * 128;
    us* h      = hcat   + (size_t)NTOK * 512;
    us* zxb    = h      + (size_t)NTOK * D_MODEL;
    us* xc     = zxb    + (size_t)NTOK * D_IN_PROJ;
    us* yn     = xc     + (size_t)NTOK * CONV_DIM;
    us* t0     = zxb;
    us* t1     = xc;
    float* fbase = (float*)((((uintptr_t)(yn + (size_t)NTOK * D_INNER)) + 255)
                            & ~(uintptr_t)255);
    float* y     = fbase;
    float* alpha = y + (size_t)NTOK * D_INNER;

    // ---- all weight transposes: ONE dispatch ----
    transpose_all_kernel<<<NT_TRANS, 256, 0, stream>>>(
        mi_w1, mi_w2, W_in, W_out, mo_w1,
        wt_mi1, wt_mi2, wt_in, wt_out, wt_mo1);

    // ---- forward ----
    concat_kernel<<<(NTOK * 512 + 255) / 256, 256, 0, stream>>>(x, steps, curr, hcat);

    mfma_gemm_f16<64, 64, 1><<<dim3(512/64, NTOK/64), 256, 0, stream>>>(
        hcat, wt_mi1, mi_b1, t0, 512, 512, 1);
    mfma_gemm_f16<64, 64, 1><<<dim3(1024/64, NTOK/64), 256, 0, stream>>>(
        t0, wt_mi2, mi_b2, h, 1024, 512, 0);

    for (int i = 0; i < NBLOCKS; ++i) {
        mfma_gemm_f16<128, 128, 4><<<dim3(NPAD_IN/128, NTOK/128), 256, 0, stream>>>(
            h, wt_in + (size_t)i * NPAD_IN * 1024, nullptr, zxb, D_IN_PROJ, D_MODEL, 0);
        conv_silu_kernel<<<(NTOK * (CONV_DIM/4) + 255) / 256, 256, 0, stream>>>(
            zxb, conv_w + (size_t)i * CONV_DIM * DCONV, conv_b + (size_t)i * CONV_DIM, xc);
        scan_seg_mfma_kernel<<<NBH * NSEG, 256, 0, stream>>>(
            zxb, xc, dt_bias + i * NHEADS, A_log + i * NHEADS, D_skip + i * NHEADS,
            y, alpha, Hseg);
        state_fixup_kernel<<<NBH * 2, 512, 0, stream>>>(alpha, Hseg);
        correct_mfma_kernel<<<NBH * (NSEG - 1), 256, 0, stream>>>(xc, alpha, Hseg, y);
        gated_rmsnorm_kernel<<<NTOK, 256, 0, stream>>>(
            y, zxb, norm_w + (size_t)i * D_INNER, yn);
        mfma_gemm_f16<64, 64, 1><<<dim3(1024/64, NTOK/64), 256, 0, stream>>>(
            yn, wt_out + (size_t)i * 1024 * 2048, nullptr, h, 1024, 2048, 0);
    }

    mfma_gemm_f16<64, 64, 1><<<dim3(1024/64, NTOK/64), 256, 0, stream>>>(
        h, wt_mo1, mo_b1, t1, 1024, 1024, 1);
    final_dot_kernel<<<NTOK, 256, 0, stream>>>(t1, mo_w2, mo_b2, out);
}